// Round 5
// baseline (227.534 us; speedup 1.0000x reference)
//
#include <hip/hip_runtime.h>

#define NUM_HEADS 8
#define DIM 64
#define NCLUST 512
#define NTOK 16384          // 8*2048 tokens
#define ROWLEN 512          // NUM_HEADS*DIM floats per token row
#define NIDS (NTOK * NUM_HEADS)           // 131072
#define NMEANS (NUM_HEADS * NCLUST * DIM) // 262144
#define NCK (NUM_HEADS * NCLUST)          // 4096
#define KSLICE 4
#define KPER 128            // clusters per slice
#define CAP 6               // slots per (slice, tokh): [0]=winner, up to 5 extras
#define DELTA 0.35f         // ~19 sigma of bf16 coarse-score noise

typedef unsigned long long u64;
typedef short bf16x8 __attribute__((ext_vector_type(8)));
typedef float f32x4 __attribute__((ext_vector_type(4)));

__device__ __forceinline__ unsigned short f2bf(float f) {   // RNE f32->bf16 bits
    unsigned b = __float_as_uint(f);
    return (unsigned short)((b + 0x7fffu + ((b >> 16) & 1u)) >> 16);
}
__device__ __forceinline__ u64 packkey(float s, int k) {    // u64 MIN == max s, tie -> min k
    unsigned u = __float_as_uint(s);
    unsigned ord = (u & 0x80000000u) ? ~u : (u | 0x80000000u);
    return ((u64)(~ord) << 32) | (unsigned)k;
}
__device__ __forceinline__ float unpacks(u64 key) {
    unsigned ord = ~(unsigned)(key >> 32);
    unsigned u = (ord & 0x80000000u) ? (ord & 0x7fffffffu) : ~ord;
    return __uint_as_float(u);
}

// ---------------- kernel 0: q[h*K+k] = 0.5*|m_hk|^2 (f32) ----------------
__global__ void vq_qnorm(const float* __restrict__ means, float* __restrict__ q) {
    int i = blockIdx.x * blockDim.x + threadIdx.x;   // 0..4095
    const float4* m = (const float4*)(means + (size_t)i * DIM);
    float s = 0.f;
#pragma unroll
    for (int j = 0; j < DIM / 4; ++j) {
        float4 v = m[j];
        s += v.x * v.x + v.y * v.y + v.z * v.z + v.w * v.w;
    }
    q[i] = 0.5f * s;
}

// ---------------- kernel 0b: means f32 -> bf16 bits ----------------
__global__ void vq_m2bf(const float* __restrict__ means, unsigned short* __restrict__ mbf) {
    int i = blockIdx.x * blockDim.x + threadIdx.x;   // 0..NMEANS-1
    mbf[i] = f2bf(means[i]);
}

// ---------------- kernel 1: coarse scores via bf16 MFMA + candidate select ----
// Block 256 thr (4 waves) = 64 tokens x 128 clusters (slice), one head.
// Wave = 16 tokens x 8 c-tiles of 16x16, K = 64 in 2 MFMA steps. acc 32 f32/lane.
// A-frag (lane l): row = l&15 (token), k = 8*(l>>4)+j  -> direct global + cvt.
// B-frag (lane l): col = l&15 (cluster), k = 8*(l>>4)+j -> bf16x8 from mbf.
// D (lane l): row = (l>>4)*4 + r (token), col = l&15 (cluster)   [m89 verified]
__global__ __launch_bounds__(256, 4) void vq_coarse(const float* __restrict__ x,
                                                    const unsigned short* __restrict__ mbf,
                                                    const float* __restrict__ q,
                                                    unsigned short* __restrict__ candK,
                                                    unsigned char* __restrict__ candN) {
    __shared__ int cnt[64];
    const int head  = blockIdx.y;
    const int slice = blockIdx.z;
    const int t0    = blockIdx.x * 64;
    const int tid   = threadIdx.x;
    const int wv = tid >> 6, l = tid & 63;
    const int lg = l >> 4, lc = l & 15;
    const int twave = t0 + wv * 16;
    const int kbase = slice * KPER;

    if (tid < 64) cnt[tid] = 0;

    f32x4 acc[8];
#pragma unroll
    for (int i = 0; i < 8; ++i) acc[i] = (f32x4){0.f, 0.f, 0.f, 0.f};

#pragma unroll
    for (int ks = 0; ks < 2; ++ks) {
        // A fragment: token twave+lc, dims ks*32 + lg*8 + (0..7)
        const float* xsrc = x + (size_t)(twave + lc) * ROWLEN + head * DIM + ks * 32 + lg * 8;
        float av[8];
        *(float4*)&av[0] = *(const float4*)xsrc;
        *(float4*)&av[4] = *(const float4*)(xsrc + 4);
        bf16x8 af;
#pragma unroll
        for (int j = 0; j < 8; ++j) af[j] = (short)f2bf(av[j]);

#pragma unroll
        for (int ct = 0; ct < 8; ++ct) {
            int k = kbase + ct * 16 + lc;
            const unsigned short* msrc =
                mbf + ((size_t)head * NCLUST + k) * DIM + ks * 32 + lg * 8;
            bf16x8 bfr = *(const bf16x8*)msrc;   // 16B aligned
            acc[ct] = __builtin_amdgcn_mfma_f32_16x16x32_bf16(af, bfr, acc[ct], 0, 0, 0);
        }
    }
    __syncthreads();   // cnt[] zeroed before any atomicAdd

    float qv[8];
#pragma unroll
    for (int ct = 0; ct < 8; ++ct) qv[ct] = q[head * NCLUST + kbase + ct * 16 + lc];

    // per-token winner key (min over packed keys) across the 16-lane col group
    u64 key[4];
#pragma unroll
    for (int r = 0; r < 4; ++r) {
        u64 kk = ~0ull;
#pragma unroll
        for (int ct = 0; ct < 8; ++ct) {
            float s = acc[ct][r] - qv[ct];
            u64 cd = packkey(s, kbase + ct * 16 + lc);
            kk = cd < kk ? cd : kk;
        }
#pragma unroll
        for (int off = 1; off < 16; off <<= 1) {
            u64 o = __shfl_xor(kk, off, 64);
            kk = o < kk ? o : kk;
        }
        key[r] = kk;
    }

    // winner write (slot 0)
    if (lc == 0) {
#pragma unroll
        for (int r = 0; r < 4; ++r) {
            int tloc = wv * 16 + lg * 4 + r;
            size_t tokh = (size_t)(t0 + tloc) * NUM_HEADS + head;
            candK[((size_t)slice * NIDS + tokh) * CAP + 0] = (unsigned short)(key[r] & 0x1ffu);
        }
    }

    // extras: anything within DELTA of winner (excluding winner itself)
#pragma unroll
    for (int r = 0; r < 4; ++r) {
        float thr = unpacks(key[r]) - DELTA;
        int wk = (int)(key[r] & 0x1ffu);
        int tloc = wv * 16 + lg * 4 + r;
        size_t tokh = (size_t)(t0 + tloc) * NUM_HEADS + head;
#pragma unroll
        for (int ct = 0; ct < 8; ++ct) {
            float s = acc[ct][r] - qv[ct];
            int k = kbase + ct * 16 + lc;
            if (s >= thr && k != wk) {
                int slot = atomicAdd(&cnt[tloc], 1);
                if (slot < CAP - 1)
                    candK[((size_t)slice * NIDS + tokh) * CAP + 1 + slot] = (unsigned short)k;
            }
        }
    }
    __syncthreads();
    if (tid < 64) {
        size_t tokh = (size_t)(t0 + tid) * NUM_HEADS + head;
        int n = cnt[tid];
        candN[(size_t)slice * NIDS + tokh] = (unsigned char)(n < CAP - 1 ? n : CAP - 1);
    }
}

// ---------------- kernel 1b: exact f32 rescore of candidates ----------------
// One 64-lane wave per (token, head); lane = dim. Butterfly-sum dot products.
__global__ __launch_bounds__(256) void vq_rescore(const float* __restrict__ x,
                                                  const float* __restrict__ means,
                                                  const float* __restrict__ q,
                                                  const unsigned short* __restrict__ candK,
                                                  const unsigned char* __restrict__ candN,
                                                  float* __restrict__ ids_f) {
    int wid = (blockIdx.x * 256 + threadIdx.x) >> 6;   // tokh 0..NIDS-1
    int lane = threadIdx.x & 63;
    int token = wid >> 3, h = wid & 7;
    float xv = x[(size_t)token * ROWLEN + h * DIM + lane];

    u64 best = ~0ull;
    for (int sl = 0; sl < KSLICE; ++sl) {
        int n = 1 + candN[(size_t)sl * NIDS + wid];
        const unsigned short* ck = candK + ((size_t)sl * NIDS + wid) * CAP;
        for (int j = 0; j < n; ++j) {
            int k = ck[j];
            float p = xv * means[((size_t)h * NCLUST + k) * DIM + lane];
#pragma unroll
            for (int off = 32; off >= 1; off >>= 1) p += __shfl_xor(p, off, 64);
            u64 cd = packkey(p - q[h * NCLUST + k], k);
            best = cd < best ? cd : best;
        }
    }
    if (lane == 0) ids_f[wid] = (float)(unsigned)(best & 0x1ffu);
}

// ---------------- kernel 2: scatter-accumulate sums & counts ----------------
__global__ void vq_scatter(const float* __restrict__ x,
                           const float* __restrict__ ids_f,
                           float* __restrict__ counts,
                           float* __restrict__ sums,
                           int rep_mask) {
    int gthread = blockIdx.x * blockDim.x + threadIdx.x;
    int w = gthread >> 6;          // pair index, 0..131071
    int lane = threadIdx.x & 63;
    int token = w >> 3;
    int h = w & 7;
    int rep = token & rep_mask;
    int id = (int)ids_f[w];        // broadcast load
    float xv = x[(size_t)token * ROWLEN + h * DIM + lane];
    atomicAdd(&sums[(size_t)rep * NMEANS + (((size_t)h * NCLUST + id) << 6) + lane], xv);
    if (lane == 0) atomicAdd(&counts[rep * NCK + h * NCLUST + id], 1.0f);
}

// ---------------- kernel 3: EMA finalize (sums replicas) ----------------
__global__ void vq_final(const float* __restrict__ means,
                         const float* __restrict__ counts,
                         const float* __restrict__ sums,
                         float* __restrict__ out_means,
                         int nrep) {
    int i = blockIdx.x * blockDim.x + threadIdx.x;   // 0..262143
    int ck = i >> 6;
    float c = 0.f, s = 0.f;
    for (int r = 0; r < nrep; ++r) {
        c += counts[r * NCK + ck];
        s += sums[(size_t)r * NMEANS + i];
    }
    float nm = s / (1e-6f + c);
    out_means[i] = 0.999f * means[i] + 0.001f * nm;
}

extern "C" void kernel_launch(void* const* d_in, const int* in_sizes, int n_in,
                              void* d_out, int out_size, void* d_ws, size_t ws_size,
                              hipStream_t stream) {
    const float* x     = (const float*)d_in[0];   // [8,2048,512]
    const float* means = (const float*)d_in[1];   // [8,512,64]

    float* out       = (float*)d_out;
    float* ids_f     = out;            // 131072 floats (cluster ids as float)
    float* out_means = out + NIDS;     // 262144 floats

    // ---- workspace layout ----
    float*          q     = (float*)d_ws;                       // NCK f32 (16 KB)
    unsigned short* mbf   = (unsigned short*)(q + NCK);         // NMEANS u16 (512 KB)
    unsigned short* candK = mbf + NMEANS;                       // KSLICE*NIDS*CAP u16 (6 MB)
    unsigned char*  candN = (unsigned char*)(candK + (size_t)KSLICE * NIDS * CAP); // 512 KB
    float*          fbase = (float*)(candN + (size_t)KSLICE * NIDS);
    size_t core = (size_t)((char*)fbase - (char*)d_ws);

    int nrep = 1;
    for (int r = 8; r > 1; r >>= 1) {
        size_t need = core + (size_t)r * (NCK + NMEANS) * sizeof(float);
        if (ws_size >= need) { nrep = r; break; }
    }
    float* counts = fbase;                        // nrep*NCK
    float* sums   = counts + (size_t)nrep * NCK;  // nrep*NMEANS

    hipMemsetAsync(counts, 0, (size_t)nrep * (NCK + NMEANS) * sizeof(float), stream);

    vq_qnorm<<<NCK / 256, 256, 0, stream>>>(means, q);
    vq_m2bf<<<NMEANS / 256, 256, 0, stream>>>(means, mbf);

    dim3 gc(NTOK / 64, NUM_HEADS, KSLICE);
    vq_coarse<<<gc, 256, 0, stream>>>(x, mbf, q, candK, candN);

    vq_rescore<<<NIDS / 4, 256, 0, stream>>>(x, means, q, candK, candN, ids_f);

    vq_scatter<<<(NIDS * 64) / 256, 256, 0, stream>>>(x, ids_f, counts, sums, nrep - 1);

    vq_final<<<NMEANS / 256, 256, 0, stream>>>(means, counts, sums, out_means, nrep);
}

// Round 7
// 118.221 us; speedup vs baseline: 1.9246x; 1.9246x over previous
//
#include <hip/hip_runtime.h>

#define NUM_HEADS 8
#define DIM 64
#define NCLUST 512
#define NTOK 16384          // 8*2048 tokens
#define ROWLEN 512          // NUM_HEADS*DIM floats per token row
#define NIDS (NTOK * NUM_HEADS)           // 131072
#define NMEANS (NUM_HEADS * NCLUST * DIM) // 262144
#define NCK (NUM_HEADS * NCLUST)          // 4096
#define TPB 128             // tokens per block in the fused score kernel
#define CAP 8               // candidate slots per token (incl. winner)
#define DELTA 0.35f         // ~19 sigma of bf16 coarse-score noise + pack quant

typedef unsigned long long u64;
typedef short bf16x8 __attribute__((ext_vector_type(8)));
typedef float f32x4 __attribute__((ext_vector_type(4)));

__device__ __forceinline__ unsigned short f2bf(float f) {   // RNE f32->bf16 bits
    unsigned b = __float_as_uint(f);
    return (unsigned short)((b + 0x7fffu + ((b >> 16) & 1u)) >> 16);
}
__device__ __forceinline__ unsigned pack2bf(float lo, float hi) {
    return (unsigned)f2bf(lo) | ((unsigned)f2bf(hi) << 16);
}
__device__ __forceinline__ u64 packkey(float s, int k) {    // u64 MIN == max s, tie -> min k
    unsigned u = __float_as_uint(s);
    unsigned ord = (u & 0x80000000u) ? ~u : (u | 0x80000000u);
    return ((u64)(~ord) << 32) | (unsigned)k;
}
// swizzled byte offset into a [rows][128B] LDS tile (G4 XOR pattern)
__device__ __forceinline__ int swz(int row, int byte_in_row) {
    return row * 128 + (byte_in_row ^ ((row & 7) << 4));
}

// ---------------- kernel 0: q[h*K+k] = 0.5*|m_hk|^2 (f32) ----------------
__global__ void vq_qnorm(const float* __restrict__ means, float* __restrict__ q) {
    int i = blockIdx.x * blockDim.x + threadIdx.x;   // 0..4095
    const float4* m = (const float4*)(means + (size_t)i * DIM);
    float s = 0.f;
#pragma unroll
    for (int j = 0; j < DIM / 4; ++j) {
        float4 v = m[j];
        s += v.x * v.x + v.y * v.y + v.z * v.z + v.w * v.w;
    }
    q[i] = 0.5f * s;
}

// ---------------- kernel 0b: means f32 -> bf16 bits ----------------
__global__ void vq_m2bf(const float* __restrict__ means, unsigned short* __restrict__ mbf) {
    int i = blockIdx.x * blockDim.x + threadIdx.x;   // 0..NMEANS-1
    mbf[i] = f2bf(means[i]);
}

// ---------------- kernel 1: fused coarse MFMA + candidate select + exact rescore ----
// Block: 256 thr (4 waves), 128 tokens, one head, all 512 clusters (2 halves of 256
// staged in LDS per sweep). Wave = 32 tokens (2 token-tiles of 16).
// MFMA 16x16x32 bf16; fragment mapping identical to the round-5-validated kernel:
//   A lane l: token row = l&15, dims ks*32 + (l>>4)*8 + 0..7
//   B lane l: cluster col = l&15, same dims
//   D lane l: col = l&15 (cluster), row = (l>>4)*4 + r (token)
// Sweep1: fold packed (score&~0x1FF)|(511-k) floats via v_max -> per-token best.
// Sweep2: recompute, insert all k with s >= best-DELTA into per-token LDS list.
// Rescore: exact f32 dot (global x/means) of each candidate, u64-min -> ids.
__global__ __launch_bounds__(256, 3) void vq_score(const float* __restrict__ x,
                                                   const float* __restrict__ means,
                                                   const unsigned short* __restrict__ mbf,
                                                   const float* __restrict__ q,
                                                   float* __restrict__ ids_f) {
    __shared__ __align__(16) unsigned char msb[256 * 128];   // 32 KB means half (swz)
    __shared__ __align__(16) unsigned char xbb[TPB * 128];   // 16 KB x tile   (swz)
    __shared__ float qs[NCLUST];                             // 2 KB
    __shared__ int cnt[TPB];                                 // 0.5 KB
    __shared__ unsigned short candL[TPB][CAP];               // 2 KB

    const int head = blockIdx.y;
    const int t0   = blockIdx.x * TPB;
    const int tid  = threadIdx.x;
    const int wv = tid >> 6, l = tid & 63;
    const int lg = l >> 4, lc = l & 15;
    const int twave = wv * 32;

    // ---- stage x tile (f32 -> bf16, swizzled) ----
#pragma unroll
    for (int it = 0; it < 2; ++it) {
        int tok = (tid >> 2) + it * 64;
        int c = tid & 3;                 // 16 dims = 64B f32 -> 32B bf16
        const float4* src = (const float4*)(x + (size_t)(t0 + tok) * ROWLEN + head * DIM + c * 16);
        float4 v0 = src[0], v1 = src[1], v2 = src[2], v3 = src[3];
        uint4 lo, hi;
        lo.x = pack2bf(v0.x, v0.y); lo.y = pack2bf(v0.z, v0.w);
        lo.z = pack2bf(v1.x, v1.y); lo.w = pack2bf(v1.z, v1.w);
        hi.x = pack2bf(v2.x, v2.y); hi.y = pack2bf(v2.z, v2.w);
        hi.z = pack2bf(v3.x, v3.y); hi.w = pack2bf(v3.z, v3.w);
        *(uint4*)(xbb + swz(tok, c * 32 + 0))  = lo;
        *(uint4*)(xbb + swz(tok, c * 32 + 16)) = hi;
    }
    // ---- stage q, zero cnt ----
    qs[tid] = q[head * NCLUST + tid];
    qs[tid + 256] = q[head * NCLUST + tid + 256];
    if (tid < TPB) cnt[tid] = 0;
    __syncthreads();

    // ---- A fragments from LDS (kept live across both sweeps) ----
    bf16x8 af[2][2];
#pragma unroll
    for (int tt = 0; tt < 2; ++tt)
#pragma unroll
        for (int ks = 0; ks < 2; ++ks)
            af[tt][ks] = *(const bf16x8*)(xbb + swz(twave + tt * 16 + lc, ks * 64 + lg * 16));

    float best[2][4];
#pragma unroll
    for (int tt = 0; tt < 2; ++tt)
#pragma unroll
        for (int r = 0; r < 4; ++r) best[tt][r] = -3.0e38f;
    float thr[2][4];

    // FIXED (round-6 bug): each thread stages ONE FULL 128-byte means row
    // (row = tid) -> all 256 rows of the half-tile are covered.
#define STAGE_MS(hf)                                                                   \
    {                                                                                  \
        const uint4* src = (const uint4*)(mbf +                                        \
            ((size_t)head * NCLUST + (hf) * 256 + tid) * DIM);                         \
        uint4 m0 = src[0], m1 = src[1], m2 = src[2], m3 = src[3];                      \
        uint4 m4 = src[4], m5 = src[5], m6 = src[6], m7 = src[7];                      \
        *(uint4*)(msb + swz(tid, 0))   = m0;                                           \
        *(uint4*)(msb + swz(tid, 16))  = m1;                                           \
        *(uint4*)(msb + swz(tid, 32))  = m2;                                           \
        *(uint4*)(msb + swz(tid, 48))  = m3;                                           \
        *(uint4*)(msb + swz(tid, 64))  = m4;                                           \
        *(uint4*)(msb + swz(tid, 80))  = m5;                                           \
        *(uint4*)(msb + swz(tid, 96))  = m6;                                           \
        *(uint4*)(msb + swz(tid, 112)) = m7;                                           \
    }

    // ================= sweep 1: packed-float argmax =================
    for (int hf = 0; hf < 2; ++hf) {
        __syncthreads();
        STAGE_MS(hf);
        __syncthreads();
        const int rbase = 511 - hf * 256 - lc;
#pragma unroll
        for (int ct = 0; ct < 16; ++ct) {
            bf16x8 b0 = *(const bf16x8*)(msb + swz(ct * 16 + lc, 0 + lg * 16));
            bf16x8 b1 = *(const bf16x8*)(msb + swz(ct * 16 + lc, 64 + lg * 16));
            float qv = qs[hf * 256 + ct * 16 + lc];
            int rk = rbase - ct * 16;
#pragma unroll
            for (int tt = 0; tt < 2; ++tt) {
                f32x4 acc = (f32x4){0.f, 0.f, 0.f, 0.f};
                acc = __builtin_amdgcn_mfma_f32_16x16x32_bf16(af[tt][0], b0, acc, 0, 0, 0);
                acc = __builtin_amdgcn_mfma_f32_16x16x32_bf16(af[tt][1], b1, acc, 0, 0, 0);
#pragma unroll
                for (int r = 0; r < 4; ++r) {
                    float s = acc[r] - qv;
                    float v = __uint_as_float((__float_as_uint(s) & 0xFFFFFE00u) | (unsigned)rk);
                    best[tt][r] = fmaxf(best[tt][r], v);
                }
            }
        }
    }
    // butterfly across the 16 cluster-lanes; all lanes converge to token max
#pragma unroll
    for (int tt = 0; tt < 2; ++tt)
#pragma unroll
        for (int r = 0; r < 4; ++r) {
#pragma unroll
            for (int off = 1; off < 16; off <<= 1)
                best[tt][r] = fmaxf(best[tt][r], __shfl_xor(best[tt][r], off, 64));
            thr[tt][r] = best[tt][r] - DELTA;
        }

    // ================= sweep 2: collect candidates within DELTA =================
    for (int hf = 0; hf < 2; ++hf) {
        __syncthreads();
        STAGE_MS(hf);
        __syncthreads();
#pragma unroll
        for (int ct = 0; ct < 16; ++ct) {
            bf16x8 b0 = *(const bf16x8*)(msb + swz(ct * 16 + lc, 0 + lg * 16));
            bf16x8 b1 = *(const bf16x8*)(msb + swz(ct * 16 + lc, 64 + lg * 16));
            float qv = qs[hf * 256 + ct * 16 + lc];
            int k = hf * 256 + ct * 16 + lc;
#pragma unroll
            for (int tt = 0; tt < 2; ++tt) {
                f32x4 acc = (f32x4){0.f, 0.f, 0.f, 0.f};
                acc = __builtin_amdgcn_mfma_f32_16x16x32_bf16(af[tt][0], b0, acc, 0, 0, 0);
                acc = __builtin_amdgcn_mfma_f32_16x16x32_bf16(af[tt][1], b1, acc, 0, 0, 0);
#pragma unroll
                for (int r = 0; r < 4; ++r) {
                    if (acc[r] >= thr[tt][r] + qv) {     // s = acc - qv >= thr
                        int tok = twave + tt * 16 + lg * 4 + r;
                        int slot = atomicAdd(&cnt[tok], 1);
                        if (slot < CAP) candL[tok][slot] = (unsigned short)k;
                    }
                }
            }
        }
    }
    __syncthreads();

    // ================= exact f32 rescore of candidates =================
    // 16-lane subgroup per token (lane lc = 4 dims); coalesced float4 reads.
#pragma unroll 2
    for (int g = 0; g < 8; ++g) {
        int tok = twave + g * 4 + lg;
        int n = cnt[tok]; n = n < CAP ? n : CAP;
        const float4 xv = *(const float4*)(x + (size_t)(t0 + tok) * ROWLEN + head * DIM + lc * 4);
        u64 bk = ~0ull;
        for (int j = 0; j < n; ++j) {
            int k = candL[tok][j];
            const float4 mv = *(const float4*)(means + ((size_t)head * NCLUST + k) * DIM + lc * 4);
            float p = fmaf(xv.x, mv.x, fmaf(xv.y, mv.y, fmaf(xv.z, mv.z, xv.w * mv.w)));
#pragma unroll
            for (int off = 1; off < 16; off <<= 1) p += __shfl_xor(p, off, 64);
            u64 cd = packkey(p - qs[k], k);
            bk = cd < bk ? cd : bk;
        }
        if (lc == 0) ids_f[(size_t)(t0 + tok) * NUM_HEADS + head] = (float)(unsigned)(bk & 0x1ffu);
    }
#undef STAGE_MS
}

// ---------------- kernel 2: scatter-accumulate sums & counts ----------------
__global__ void vq_scatter(const float* __restrict__ x,
                           const float* __restrict__ ids_f,
                           float* __restrict__ counts,
                           float* __restrict__ sums,
                           int rep_mask) {
    int gthread = blockIdx.x * blockDim.x + threadIdx.x;
    int w = gthread >> 6;          // pair index, 0..131071
    int lane = threadIdx.x & 63;
    int token = w >> 3;
    int h = w & 7;
    int rep = token & rep_mask;
    int id = (int)ids_f[w];        // broadcast load
    float xv = x[(size_t)token * ROWLEN + h * DIM + lane];
    atomicAdd(&sums[(size_t)rep * NMEANS + (((size_t)h * NCLUST + id) << 6) + lane], xv);
    if (lane == 0) atomicAdd(&counts[rep * NCK + h * NCLUST + id], 1.0f);
}

// ---------------- kernel 3: EMA finalize (sums replicas) ----------------
__global__ void vq_final(const float* __restrict__ means,
                         const float* __restrict__ counts,
                         const float* __restrict__ sums,
                         float* __restrict__ out_means,
                         int nrep) {
    int i = blockIdx.x * blockDim.x + threadIdx.x;   // 0..262143
    int ck = i >> 6;
    float c = 0.f, s = 0.f;
    for (int r = 0; r < nrep; ++r) {
        c += counts[r * NCK + ck];
        s += sums[(size_t)r * NMEANS + i];
    }
    float nm = s / (1e-6f + c);
    out_means[i] = 0.999f * means[i] + 0.001f * nm;
}

extern "C" void kernel_launch(void* const* d_in, const int* in_sizes, int n_in,
                              void* d_out, int out_size, void* d_ws, size_t ws_size,
                              hipStream_t stream) {
    const float* x     = (const float*)d_in[0];   // [8,2048,512]
    const float* means = (const float*)d_in[1];   // [8,512,64]

    float* out       = (float*)d_out;
    float* ids_f     = out;            // 131072 floats (cluster ids as float)
    float* out_means = out + NIDS;     // 262144 floats

    // ---- workspace layout ----
    float*          q   = (float*)d_ws;                 // NCK f32 (16 KB)
    unsigned short* mbf = (unsigned short*)(q + NCK);   // NMEANS u16 (512 KB)
    float*          fbase = (float*)(mbf + NMEANS);
    size_t core = (size_t)((char*)fbase - (char*)d_ws);

    int nrep = 1;
    for (int r = 8; r > 1; r >>= 1) {
        size_t need = core + (size_t)r * (NCK + NMEANS) * sizeof(float);
        if (ws_size >= need) { nrep = r; break; }
    }
    float* counts = fbase;                        // nrep*NCK
    float* sums   = counts + (size_t)nrep * NCK;  // nrep*NMEANS

    hipMemsetAsync(counts, 0, (size_t)nrep * (NCK + NMEANS) * sizeof(float), stream);

    vq_qnorm<<<NCK / 256, 256, 0, stream>>>(means, q);
    vq_m2bf<<<NMEANS / 256, 256, 0, stream>>>(means, mbf);

    dim3 gs(NTOK / TPB, NUM_HEADS);
    vq_score<<<gs, 256, 0, stream>>>(x, means, mbf, q, ids_f);

    vq_scatter<<<(NIDS * 64) / 256, 256, 0, stream>>>(x, ids_f, counts, sums, nrep - 1);

    vq_final<<<NMEANS / 256, 256, 0, stream>>>(means, counts, sums, out_means, nrep);
}

// Round 8
// 92.839 us; speedup vs baseline: 2.4508x; 1.2734x over previous
//
#include <hip/hip_runtime.h>

#define NUM_HEADS 8
#define DIM 64
#define NCLUST 512
#define NTOK 16384          // 8*2048 tokens
#define ROWLEN 512          // NUM_HEADS*DIM floats per token row
#define NIDS (NTOK * NUM_HEADS)           // 131072
#define NMEANS (NUM_HEADS * NCLUST * DIM) // 262144
#define NCK (NUM_HEADS * NCLUST)          // 4096
#define TPB 128             // tokens per block in the fused score kernel
#define KQ 128              // clusters per staged quarter
#define CAP 8               // candidate slots per token (incl. winner)
#define DELTA 0.35f         // ~19 sigma of bf16 coarse-score noise + pack quant

typedef unsigned long long u64;
typedef short bf16x8 __attribute__((ext_vector_type(8)));
typedef float f32x4 __attribute__((ext_vector_type(4)));

__device__ __forceinline__ unsigned short f2bf(float f) {   // RNE f32->bf16 bits
    unsigned b = __float_as_uint(f);
    return (unsigned short)((b + 0x7fffu + ((b >> 16) & 1u)) >> 16);
}
__device__ __forceinline__ unsigned pack2bf(float lo, float hi) {
    return (unsigned)f2bf(lo) | ((unsigned)f2bf(hi) << 16);
}
__device__ __forceinline__ u64 packkey(float s, int k) {    // u64 MIN == max s, tie -> min k
    unsigned u = __float_as_uint(s);
    unsigned ord = (u & 0x80000000u) ? ~u : (u | 0x80000000u);
    return ((u64)(~ord) << 32) | (unsigned)k;
}
// swizzled byte offset into a [rows][128B] LDS tile (G4 XOR pattern)
__device__ __forceinline__ int swz(int row, int byte_in_row) {
    return row * 128 + (byte_in_row ^ ((row & 7) << 4));
}

// ---------------- kernel 0: fused prep: q = 0.5*|m|^2 and means f32->bf16 ----
// 16 lanes per cluster-row; coalesced float4 reads, ushort4 writes.
__global__ void vq_prep(const float* __restrict__ means,
                        float* __restrict__ q,
                        unsigned short* __restrict__ mbf) {
    int g = blockIdx.x * blockDim.x + threadIdx.x;   // 0..65535
    int row = g >> 4, c = g & 15;
    float4 v = *(const float4*)(means + (size_t)row * DIM + c * 4);
    ushort4 b;
    b.x = f2bf(v.x); b.y = f2bf(v.y); b.z = f2bf(v.z); b.w = f2bf(v.w);
    *(ushort4*)(mbf + (size_t)row * DIM + c * 4) = b;
    float s = fmaf(v.x, v.x, fmaf(v.y, v.y, fmaf(v.z, v.z, v.w * v.w)));
#pragma unroll
    for (int off = 1; off < 16; off <<= 1) s += __shfl_xor(s, off, 64);
    if (c == 0) q[row] = 0.5f * s;
}

// ---------------- kernel 1: fused coarse MFMA + candidate select + exact rescore ----
// Block: 256 thr (4 waves), 128 tokens, one head, all 512 clusters staged in
// QUARTERS of 128 (16KB) -> LDS ~37.4KB -> 4 blocks/CU (16 waves/CU).
// Wave = 32 tokens (2 token-tiles of 16). MFMA 16x16x32 bf16, mapping as validated:
//   A lane l: token row = l&15, dims ks*32 + (l>>4)*8 + 0..7
//   B lane l: cluster col = l&15, same dims
//   D lane l: col = l&15 (cluster), row = (l>>4)*4 + r (token)
// Sweep1: fold packed (score&~0x1FF)|(511-k) floats via v_max -> per-token best.
// Sweep2: recompute, insert all k with s >= best-DELTA into per-token LDS list.
// Rescore: exact f32 dot (global x/means) of each candidate, u64-min -> ids.
__global__ __launch_bounds__(256, 4) void vq_score(const float* __restrict__ x,
                                                   const float* __restrict__ means,
                                                   const unsigned short* __restrict__ mbf,
                                                   const float* __restrict__ q,
                                                   float* __restrict__ ids_f) {
    __shared__ __align__(16) unsigned char msq[KQ * 128];    // 16 KB means quarter (swz)
    __shared__ __align__(16) unsigned char xbb[TPB * 128];   // 16 KB x tile (swz)
    __shared__ float qs[NCLUST];                             // 2 KB
    __shared__ int cnt[TPB];                                 // 0.5 KB
    __shared__ unsigned short candL[TPB][CAP];               // 2 KB

    const int head = blockIdx.y;
    const int t0   = blockIdx.x * TPB;
    const int tid  = threadIdx.x;
    const int wv = tid >> 6, l = tid & 63;
    const int lg = l >> 4, lc = l & 15;
    const int twave = wv * 32;

    // ---- stage x tile (f32 -> bf16, swizzled) ----
#pragma unroll
    for (int it = 0; it < 2; ++it) {
        int tok = (tid >> 2) + it * 64;
        int c = tid & 3;                 // 16 dims = 64B f32 -> 32B bf16
        const float4* src = (const float4*)(x + (size_t)(t0 + tok) * ROWLEN + head * DIM + c * 16);
        float4 v0 = src[0], v1 = src[1], v2 = src[2], v3 = src[3];
        uint4 lo, hi;
        lo.x = pack2bf(v0.x, v0.y); lo.y = pack2bf(v0.z, v0.w);
        lo.z = pack2bf(v1.x, v1.y); lo.w = pack2bf(v1.z, v1.w);
        hi.x = pack2bf(v2.x, v2.y); hi.y = pack2bf(v2.z, v2.w);
        hi.z = pack2bf(v3.x, v3.y); hi.w = pack2bf(v3.z, v3.w);
        *(uint4*)(xbb + swz(tok, c * 32 + 0))  = lo;
        *(uint4*)(xbb + swz(tok, c * 32 + 16)) = hi;
    }
    // ---- stage q, zero cnt ----
    qs[tid] = q[head * NCLUST + tid];
    qs[tid + 256] = q[head * NCLUST + tid + 256];
    if (tid < TPB) cnt[tid] = 0;
    __syncthreads();

    // ---- A fragments from LDS (kept live across both sweeps) ----
    bf16x8 af[2][2];
#pragma unroll
    for (int tt = 0; tt < 2; ++tt)
#pragma unroll
        for (int ks = 0; ks < 2; ++ks)
            af[tt][ks] = *(const bf16x8*)(xbb + swz(twave + tt * 16 + lc, ks * 64 + lg * 16));

    float best[2][4];
#pragma unroll
    for (int tt = 0; tt < 2; ++tt)
#pragma unroll
        for (int r = 0; r < 4; ++r) best[tt][r] = -3.0e38f;
    float thr[2][4];

    // stage one 128-cluster quarter: thread stages HALF a 128B row
    // (row = tid>>1 covers rows 0..127 exactly; c = tid&1 selects 64B half)
#define STAGE_MS(qt)                                                                   \
    {                                                                                  \
        int row = tid >> 1, c = tid & 1;                                               \
        const uint4* src = (const uint4*)(mbf +                                        \
            ((size_t)head * NCLUST + (qt) * KQ + row) * DIM + c * 32);                 \
        uint4 m0 = src[0], m1 = src[1], m2 = src[2], m3 = src[3];                      \
        *(uint4*)(msq + swz(row, c * 64 + 0))  = m0;                                   \
        *(uint4*)(msq + swz(row, c * 64 + 16)) = m1;                                   \
        *(uint4*)(msq + swz(row, c * 64 + 32)) = m2;                                   \
        *(uint4*)(msq + swz(row, c * 64 + 48)) = m3;                                   \
    }

    // ================= sweep 1: packed-float argmax =================
    for (int qt = 0; qt < NCLUST / KQ; ++qt) {
        __syncthreads();
        STAGE_MS(qt);
        __syncthreads();
        const int rbase = 511 - qt * KQ - lc;
#pragma unroll
        for (int ct = 0; ct < KQ / 16; ++ct) {
            bf16x8 b0 = *(const bf16x8*)(msq + swz(ct * 16 + lc, 0 + lg * 16));
            bf16x8 b1 = *(const bf16x8*)(msq + swz(ct * 16 + lc, 64 + lg * 16));
            float qv = qs[qt * KQ + ct * 16 + lc];
            int rk = rbase - ct * 16;
#pragma unroll
            for (int tt = 0; tt < 2; ++tt) {
                f32x4 acc = (f32x4){0.f, 0.f, 0.f, 0.f};
                acc = __builtin_amdgcn_mfma_f32_16x16x32_bf16(af[tt][0], b0, acc, 0, 0, 0);
                acc = __builtin_amdgcn_mfma_f32_16x16x32_bf16(af[tt][1], b1, acc, 0, 0, 0);
#pragma unroll
                for (int r = 0; r < 4; ++r) {
                    float s = acc[r] - qv;
                    float v = __uint_as_float((__float_as_uint(s) & 0xFFFFFE00u) | (unsigned)rk);
                    best[tt][r] = fmaxf(best[tt][r], v);
                }
            }
        }
    }
    // butterfly across the 16 cluster-lanes; all lanes converge to token max
#pragma unroll
    for (int tt = 0; tt < 2; ++tt)
#pragma unroll
        for (int r = 0; r < 4; ++r) {
#pragma unroll
            for (int off = 1; off < 16; off <<= 1)
                best[tt][r] = fmaxf(best[tt][r], __shfl_xor(best[tt][r], off, 64));
            thr[tt][r] = best[tt][r] - DELTA;
        }

    // ================= sweep 2: collect candidates within DELTA =================
    for (int qt = 0; qt < NCLUST / KQ; ++qt) {
        __syncthreads();
        STAGE_MS(qt);
        __syncthreads();
#pragma unroll
        for (int ct = 0; ct < KQ / 16; ++ct) {
            bf16x8 b0 = *(const bf16x8*)(msq + swz(ct * 16 + lc, 0 + lg * 16));
            bf16x8 b1 = *(const bf16x8*)(msq + swz(ct * 16 + lc, 64 + lg * 16));
            float qv = qs[qt * KQ + ct * 16 + lc];
            int k = qt * KQ + ct * 16 + lc;
#pragma unroll
            for (int tt = 0; tt < 2; ++tt) {
                f32x4 acc = (f32x4){0.f, 0.f, 0.f, 0.f};
                acc = __builtin_amdgcn_mfma_f32_16x16x32_bf16(af[tt][0], b0, acc, 0, 0, 0);
                acc = __builtin_amdgcn_mfma_f32_16x16x32_bf16(af[tt][1], b1, acc, 0, 0, 0);
#pragma unroll
                for (int r = 0; r < 4; ++r) {
                    if (acc[r] >= thr[tt][r] + qv) {     // s = acc - qv >= thr
                        int tok = twave + tt * 16 + lg * 4 + r;
                        int slot = atomicAdd(&cnt[tok], 1);
                        if (slot < CAP) candL[tok][slot] = (unsigned short)k;
                    }
                }
            }
        }
    }
    __syncthreads();

    // ================= exact f32 rescore of candidates =================
    // 16-lane subgroup per token (lane lc = 4 dims); coalesced float4 reads.
#pragma unroll 2
    for (int g = 0; g < 8; ++g) {
        int tok = twave + g * 4 + lg;
        int n = cnt[tok]; n = n < CAP ? n : CAP;
        const float4 xv = *(const float4*)(x + (size_t)(t0 + tok) * ROWLEN + head * DIM + lc * 4);
        u64 bk = ~0ull;
        for (int j = 0; j < n; ++j) {
            int k = candL[tok][j];
            const float4 mv = *(const float4*)(means + ((size_t)head * NCLUST + k) * DIM + lc * 4);
            float p = fmaf(xv.x, mv.x, fmaf(xv.y, mv.y, fmaf(xv.z, mv.z, xv.w * mv.w)));
#pragma unroll
            for (int off = 1; off < 16; off <<= 1) p += __shfl_xor(p, off, 64);
            u64 cd = packkey(p - qs[k], k);
            bk = cd < bk ? cd : bk;
        }
        if (lc == 0) ids_f[(size_t)(t0 + tok) * NUM_HEADS + head] = (float)(unsigned)(bk & 0x1ffu);
    }
#undef STAGE_MS
}

// ---------------- kernel 2: scatter-accumulate sums & counts ----------------
__global__ void vq_scatter(const float* __restrict__ x,
                           const float* __restrict__ ids_f,
                           float* __restrict__ counts,
                           float* __restrict__ sums,
                           int rep_mask) {
    int gthread = blockIdx.x * blockDim.x + threadIdx.x;
    int w = gthread >> 6;          // pair index, 0..131071
    int lane = threadIdx.x & 63;
    int token = w >> 3;
    int h = w & 7;
    int rep = token & rep_mask;
    int id = (int)ids_f[w];        // broadcast load
    float xv = x[(size_t)token * ROWLEN + h * DIM + lane];
    atomicAdd(&sums[(size_t)rep * NMEANS + (((size_t)h * NCLUST + id) << 6) + lane], xv);
    if (lane == 0) atomicAdd(&counts[rep * NCK + h * NCLUST + id], 1.0f);
}

// ---------------- kernel 3: EMA finalize (sums replicas) ----------------
__global__ void vq_final(const float* __restrict__ means,
                         const float* __restrict__ counts,
                         const float* __restrict__ sums,
                         float* __restrict__ out_means,
                         int nrep) {
    int i = blockIdx.x * blockDim.x + threadIdx.x;   // 0..262143
    int ck = i >> 6;
    float c = 0.f, s = 0.f;
    for (int r = 0; r < nrep; ++r) {
        c += counts[r * NCK + ck];
        s += sums[(size_t)r * NMEANS + i];
    }
    float nm = s / (1e-6f + c);
    out_means[i] = 0.999f * means[i] + 0.001f * nm;
}

extern "C" void kernel_launch(void* const* d_in, const int* in_sizes, int n_in,
                              void* d_out, int out_size, void* d_ws, size_t ws_size,
                              hipStream_t stream) {
    const float* x     = (const float*)d_in[0];   // [8,2048,512]
    const float* means = (const float*)d_in[1];   // [8,512,64]

    float* out       = (float*)d_out;
    float* ids_f     = out;            // 131072 floats (cluster ids as float)
    float* out_means = out + NIDS;     // 262144 floats

    // ---- workspace layout ----
    float*          q   = (float*)d_ws;                 // NCK f32 (16 KB)
    unsigned short* mbf = (unsigned short*)(q + NCK);   // NMEANS u16 (512 KB)
    float*          fbase = (float*)(mbf + NMEANS);
    size_t core = (size_t)((char*)fbase - (char*)d_ws);

    int nrep = 1;
    for (int r = 8; r > 1; r >>= 1) {
        size_t need = core + (size_t)r * (NCK + NMEANS) * sizeof(float);
        if (ws_size >= need) { nrep = r; break; }
    }
    float* counts = fbase;                        // nrep*NCK
    float* sums   = counts + (size_t)nrep * NCK;  // nrep*NMEANS

    hipMemsetAsync(counts, 0, (size_t)nrep * (NCK + NMEANS) * sizeof(float), stream);

    vq_prep<<<(NCK * 16) / 256, 256, 0, stream>>>(means, q, mbf);

    dim3 gs(NTOK / TPB, NUM_HEADS);
    vq_score<<<gs, 256, 0, stream>>>(x, means, mbf, q, ids_f);

    vq_scatter<<<(NIDS * 64) / 256, 256, 0, stream>>>(x, ids_f, counts, sums, nrep - 1);

    vq_final<<<NMEANS / 256, 256, 0, stream>>>(means, counts, sums, out_means, nrep);
}

// Round 9
// 78.136 us; speedup vs baseline: 2.9120x; 1.1882x over previous
//
#include <hip/hip_runtime.h>

#define NUM_HEADS 8
#define DIM 64
#define NCLUST 512
#define NTOK 16384          // 8*2048 tokens
#define ROWLEN 512          // NUM_HEADS*DIM floats per token row
#define NIDS (NTOK * NUM_HEADS)           // 131072
#define NMEANS (NUM_HEADS * NCLUST * DIM) // 262144
#define NCK (NUM_HEADS * NCLUST)          // 4096
#define TPB 128             // tokens per block in the fused score kernel
#define KQ 128              // clusters per staged quarter
#define CAP 8               // candidate slots per token (incl. winner)
#define DELTA 0.35f         // ~19 sigma of bf16 coarse-score noise + pack quant

typedef unsigned long long u64;
typedef short bf16x8 __attribute__((ext_vector_type(8)));
typedef float f32x4 __attribute__((ext_vector_type(4)));

__device__ __forceinline__ unsigned short f2bf(float f) {   // RNE f32->bf16 bits
    unsigned b = __float_as_uint(f);
    return (unsigned short)((b + 0x7fffu + ((b >> 16) & 1u)) >> 16);
}
__device__ __forceinline__ unsigned pack2bf(float lo, float hi) {
    return (unsigned)f2bf(lo) | ((unsigned)f2bf(hi) << 16);
}
__device__ __forceinline__ float bf2f(unsigned short b) {
    return __uint_as_float((unsigned)b << 16);
}
__device__ __forceinline__ u64 packkey(float s, int k) {    // u64 MIN == max s, tie -> min k
    unsigned u = __float_as_uint(s);
    unsigned ord = (u & 0x80000000u) ? ~u : (u | 0x80000000u);
    return ((u64)(~ord) << 32) | (unsigned)k;
}
// swizzled byte offset into a [rows][128B] LDS tile (G4 XOR pattern)
__device__ __forceinline__ int swz(int row, int byte_in_row) {
    return row * 128 + (byte_in_row ^ ((row & 7) << 4));
}

// ---------------- kernel 0: fused prep: q = 0.5*|m|^2 and means f32->bf16 ----
__global__ void vq_prep(const float* __restrict__ means,
                        float* __restrict__ q,
                        unsigned short* __restrict__ mbf) {
    int g = blockIdx.x * blockDim.x + threadIdx.x;   // 0..65535
    int row = g >> 4, c = g & 15;
    float4 v = *(const float4*)(means + (size_t)row * DIM + c * 4);
    ushort4 b;
    b.x = f2bf(v.x); b.y = f2bf(v.y); b.z = f2bf(v.z); b.w = f2bf(v.w);
    *(ushort4*)(mbf + (size_t)row * DIM + c * 4) = b;
    float s = fmaf(v.x, v.x, fmaf(v.y, v.y, fmaf(v.z, v.z, v.w * v.w)));
#pragma unroll
    for (int off = 1; off < 16; off <<= 1) s += __shfl_xor(s, off, 64);
    if (c == 0) q[row] = 0.5f * s;
}

// ---------------- kernel 1: fused coarse MFMA + candidate select + exact rescore ----
// Async-staged (T14): each quarter's global loads issued one phase early into
// registers; ds_write after the barrier. Sweep2 runs quarters in REVERSE order
// so quarter 3 (already in LDS) needs no restage. acc initialized with -q_k
// (MFMA C-in) so acc output IS the score. LDS ~37.4KB -> 4 blocks/CU.
__global__ __launch_bounds__(256, 4) void vq_score(const float* __restrict__ x,
                                                   const float* __restrict__ means,
                                                   const unsigned short* __restrict__ mbf,
                                                   const float* __restrict__ q,
                                                   float* __restrict__ ids_f) {
    __shared__ __align__(16) unsigned char msq[KQ * 128];    // 16 KB means quarter (swz)
    __shared__ __align__(16) unsigned char xbb[TPB * 128];   // 16 KB x tile (swz)
    __shared__ float qs[NCLUST];                             // 2 KB
    __shared__ int cnt[TPB];                                 // 0.5 KB
    __shared__ unsigned short candL[TPB][CAP];               // 2 KB

    const int head = blockIdx.y;
    const int t0   = blockIdx.x * TPB;
    const int tid  = threadIdx.x;
    const int wv = tid >> 6, l = tid & 63;
    const int lg = l >> 4, lc = l & 15;
    const int twave = wv * 32;

    uint4 pf0, pf1, pf2, pf3;            // prefetch registers for one means quarter
    auto loadq = [&](int qt) {
        int row = tid >> 1, c = tid & 1;
        const uint4* src = (const uint4*)(mbf +
            ((size_t)head * NCLUST + qt * KQ + row) * DIM + c * 32);
        pf0 = src[0]; pf1 = src[1]; pf2 = src[2]; pf3 = src[3];
    };
    auto writems = [&]() {
        int row = tid >> 1, c = tid & 1;
        *(uint4*)(msq + swz(row, c * 64 + 0))  = pf0;
        *(uint4*)(msq + swz(row, c * 64 + 16)) = pf1;
        *(uint4*)(msq + swz(row, c * 64 + 32)) = pf2;
        *(uint4*)(msq + swz(row, c * 64 + 48)) = pf3;
    };

    // ---- stage x tile (f32 -> bf16, swizzled) ----
#pragma unroll
    for (int it = 0; it < 2; ++it) {
        int tok = (tid >> 2) + it * 64;
        int c = tid & 3;                 // 16 dims = 64B f32 -> 32B bf16
        const float4* src = (const float4*)(x + (size_t)(t0 + tok) * ROWLEN + head * DIM + c * 16);
        float4 v0 = src[0], v1 = src[1], v2 = src[2], v3 = src[3];
        uint4 lo, hi;
        lo.x = pack2bf(v0.x, v0.y); lo.y = pack2bf(v0.z, v0.w);
        lo.z = pack2bf(v1.x, v1.y); lo.w = pack2bf(v1.z, v1.w);
        hi.x = pack2bf(v2.x, v2.y); hi.y = pack2bf(v2.z, v2.w);
        hi.z = pack2bf(v3.x, v3.y); hi.w = pack2bf(v3.z, v3.w);
        *(uint4*)(xbb + swz(tok, c * 32 + 0))  = lo;
        *(uint4*)(xbb + swz(tok, c * 32 + 16)) = hi;
    }
    // ---- stage q, zero cnt, prefetch quarter 0 ----
    qs[tid] = q[head * NCLUST + tid];
    qs[tid + 256] = q[head * NCLUST + tid + 256];
    if (tid < TPB) cnt[tid] = 0;
    loadq(0);
    __syncthreads();

    // ---- A fragments from LDS (kept live across both sweeps) ----
    bf16x8 af[2][2];
#pragma unroll
    for (int tt = 0; tt < 2; ++tt)
#pragma unroll
        for (int ks = 0; ks < 2; ++ks)
            af[tt][ks] = *(const bf16x8*)(xbb + swz(twave + tt * 16 + lc, ks * 64 + lg * 16));

    float best[2][4];
#pragma unroll
    for (int tt = 0; tt < 2; ++tt)
#pragma unroll
        for (int r = 0; r < 4; ++r) best[tt][r] = -3.0e38f;
    float thr[2][4];

    auto sweep1_q = [&](int qt) {
        const int rbase = 511 - qt * KQ - lc;
#pragma unroll
        for (int ct = 0; ct < KQ / 16; ++ct) {
            bf16x8 b0 = *(const bf16x8*)(msq + swz(ct * 16 + lc, 0 + lg * 16));
            bf16x8 b1 = *(const bf16x8*)(msq + swz(ct * 16 + lc, 64 + lg * 16));
            float qv = qs[qt * KQ + ct * 16 + lc];
            int rk = rbase - ct * 16;
#pragma unroll
            for (int tt = 0; tt < 2; ++tt) {
                f32x4 acc = (f32x4){-qv, -qv, -qv, -qv};   // C-in = -q_k: acc out == score
                acc = __builtin_amdgcn_mfma_f32_16x16x32_bf16(af[tt][0], b0, acc, 0, 0, 0);
                acc = __builtin_amdgcn_mfma_f32_16x16x32_bf16(af[tt][1], b1, acc, 0, 0, 0);
#pragma unroll
                for (int r = 0; r < 4; ++r) {
                    float v = __uint_as_float((__float_as_uint(acc[r]) & 0xFFFFFE00u) | (unsigned)rk);
                    best[tt][r] = fmaxf(best[tt][r], v);
                }
            }
        }
    };
    auto collect_q = [&](int qt) {
#pragma unroll
        for (int ct = 0; ct < KQ / 16; ++ct) {
            bf16x8 b0 = *(const bf16x8*)(msq + swz(ct * 16 + lc, 0 + lg * 16));
            bf16x8 b1 = *(const bf16x8*)(msq + swz(ct * 16 + lc, 64 + lg * 16));
            float qv = qs[qt * KQ + ct * 16 + lc];
            int k = qt * KQ + ct * 16 + lc;
#pragma unroll
            for (int tt = 0; tt < 2; ++tt) {
                f32x4 acc = (f32x4){-qv, -qv, -qv, -qv};
                acc = __builtin_amdgcn_mfma_f32_16x16x32_bf16(af[tt][0], b0, acc, 0, 0, 0);
                acc = __builtin_amdgcn_mfma_f32_16x16x32_bf16(af[tt][1], b1, acc, 0, 0, 0);
#pragma unroll
                for (int r = 0; r < 4; ++r) {
                    if (acc[r] >= thr[tt][r]) {
                        int tok = twave + tt * 16 + lg * 4 + r;
                        int slot = atomicAdd(&cnt[tok], 1);
                        if (slot < CAP) candL[tok][slot] = (unsigned short)k;
                    }
                }
            }
        }
    };

    // ================= sweep 1 (quarters 0..3, prefetched) =================
    for (int qt = 0; qt < 4; ++qt) {
        __syncthreads();                  // readers done with previous msq content
        writems();                        // waits on loadq's vmcnt automatically
        if (qt < 3) loadq(qt + 1);        // next quarter in flight during compute
        __syncthreads();
        sweep1_q(qt);
    }
    // butterfly across the 16 cluster-lanes; all lanes converge to token max
#pragma unroll
    for (int tt = 0; tt < 2; ++tt)
#pragma unroll
        for (int r = 0; r < 4; ++r) {
#pragma unroll
            for (int off = 1; off < 16; off <<= 1)
                best[tt][r] = fmaxf(best[tt][r], __shfl_xor(best[tt][r], off, 64));
            thr[tt][r] = best[tt][r] - DELTA;
        }

    // ================= sweep 2 (reverse order: q3 already staged) ============
    loadq(2);
    collect_q(3);                         // msq still holds quarter 3 (read-only reuse)
    for (int qt = 2; qt >= 0; --qt) {
        __syncthreads();
        writems();
        if (qt > 0) loadq(qt - 1);
        __syncthreads();
        collect_q(qt);
    }
    __syncthreads();

    // ================= exact f32 rescore of candidates =================
#pragma unroll 2
    for (int g = 0; g < 8; ++g) {
        int tok = twave + g * 4 + lg;
        int n = cnt[tok]; n = n < CAP ? n : CAP;
        const float4 xv = *(const float4*)(x + (size_t)(t0 + tok) * ROWLEN + head * DIM + lc * 4);
        u64 bk = ~0ull;
        for (int j = 0; j < n; ++j) {
            int k = candL[tok][j];
            const float4 mv = *(const float4*)(means + ((size_t)head * NCLUST + k) * DIM + lc * 4);
            float p = fmaf(xv.x, mv.x, fmaf(xv.y, mv.y, fmaf(xv.z, mv.z, xv.w * mv.w)));
#pragma unroll
            for (int off = 1; off < 16; off <<= 1) p += __shfl_xor(p, off, 64);
            u64 cd = packkey(p - qs[k], k);
            bk = cd < bk ? cd : bk;
        }
        if (lc == 0) ids_f[(size_t)(t0 + tok) * NUM_HEADS + head] = (float)(unsigned)(bk & 0x1ffu);
    }
}

// ---------------- kernel 2: scatter via packed bf16 atomics ----------------
// 32 lanes per (token, head); lane handles dims {2l, 2l+1} with ONE
// global_atomic_pk_add_bf16 (gfx950-native) -> half the atomic ops of f32.
__global__ void vq_scatter(const float* __restrict__ x,
                           const float* __restrict__ ids_f,
                           float* __restrict__ counts,
                           unsigned short* __restrict__ sums_bf,
                           int rep_mask) {
    int g = blockIdx.x * blockDim.x + threadIdx.x;
    int p = g >> 5;                      // pair index, 0..131071
    int l32 = threadIdx.x & 31;
    int token = p >> 3;
    int h = p & 7;
    int rep = token & rep_mask;
    int id = (int)ids_f[p];              // broadcast load
    float2 xv = *(const float2*)(x + (size_t)token * ROWLEN + h * DIM + l32 * 2);
    unsigned val = pack2bf(xv.x, xv.y);
    unsigned short* dst = sums_bf + (size_t)rep * NMEANS
                        + (((size_t)h * NCLUST + id) << 6) + l32 * 2;
    asm volatile("global_atomic_pk_add_bf16 %0, %1, off" :: "v"(dst), "v"(val) : "memory");
    if (l32 == 0) atomicAdd(&counts[rep * NCK + h * NCLUST + id], 1.0f);
}

// ---------------- kernel 3: EMA finalize (sums replicas, bf16) ----------------
__global__ void vq_final(const float* __restrict__ means,
                         const float* __restrict__ counts,
                         const unsigned short* __restrict__ sums_bf,
                         float* __restrict__ out_means,
                         int nrep) {
    int i = blockIdx.x * blockDim.x + threadIdx.x;   // 0..262143
    int ck = i >> 6;
    float c = 0.f, s = 0.f;
    for (int r = 0; r < nrep; ++r) {
        c += counts[r * NCK + ck];
        s += bf2f(sums_bf[(size_t)r * NMEANS + i]);
    }
    float nm = s / (1e-6f + c);
    out_means[i] = 0.999f * means[i] + 0.001f * nm;
}

extern "C" void kernel_launch(void* const* d_in, const int* in_sizes, int n_in,
                              void* d_out, int out_size, void* d_ws, size_t ws_size,
                              hipStream_t stream) {
    const float* x     = (const float*)d_in[0];   // [8,2048,512]
    const float* means = (const float*)d_in[1];   // [8,512,64]

    float* out       = (float*)d_out;
    float* ids_f     = out;            // 131072 floats (cluster ids as float)
    float* out_means = out + NIDS;     // 262144 floats

    // ---- workspace layout ----
    float*          q   = (float*)d_ws;                 // NCK f32 (16 KB)
    unsigned short* mbf = (unsigned short*)(q + NCK);   // NMEANS u16 (512 KB)
    float*          fbase = (float*)(mbf + NMEANS);
    size_t core = (size_t)((char*)fbase - (char*)d_ws);

    size_t per_rep = (size_t)NCK * sizeof(float) + (size_t)NMEANS * sizeof(unsigned short);
    int nrep = 1;
    for (int r = 8; r > 1; r >>= 1) {
        if (ws_size >= core + (size_t)r * per_rep) { nrep = r; break; }
    }
    float*          counts  = fbase;                                   // nrep*NCK f32
    unsigned short* sums_bf = (unsigned short*)(counts + (size_t)nrep * NCK); // nrep*NMEANS u16

    hipMemsetAsync(counts, 0, (size_t)nrep * per_rep, stream);

    vq_prep<<<(NCK * 16) / 256, 256, 0, stream>>>(means, q, mbf);

    dim3 gs(NTOK / TPB, NUM_HEADS);
    vq_score<<<gs, 256, 0, stream>>>(x, means, mbf, q, ids_f);

    vq_scatter<<<(NIDS * 32) / 256, 256, 0, stream>>>(x, ids_f, counts, sums_bf, nrep - 1);

    vq_final<<<NMEANS / 256, 256, 0, stream>>>(means, counts, sums_bf, out_means, nrep);
}